// Round 4
// baseline (302.557 us; speedup 1.0000x reference)
//
#include <hip/hip_runtime.h>
#include <hip/hip_bf16.h>
#include <type_traits>

typedef __bf16 bf16;
typedef __bf16 bf16x8 __attribute__((ext_vector_type(8)));
typedef float floatx4 __attribute__((ext_vector_type(4)));

#define QLD 72    // 64 + 8 pad
#define KLD 136   // 128 + 8 pad

#if __has_builtin(__builtin_amdgcn_exp2f)
#define EXP2(x) __builtin_amdgcn_exp2f(x)
#else
#define EXP2(x) exp2f(x)
#endif

__device__ __forceinline__ void glds16(const bf16* g, bf16* l) {
  __builtin_amdgcn_global_load_lds((const __attribute__((address_space(1))) void*)g,
                                   (__attribute__((address_space(3))) void*)l, 16, 0, 0);
}

__device__ __forceinline__ unsigned pack_bf16(float a, float b) {
  unsigned short ua = __builtin_bit_cast(unsigned short, (bf16)a);
  unsigned short ub = __builtin_bit_cast(unsigned short, (bf16)b);
  return (unsigned)ua | ((unsigned)ub << 16);
}

// ---------------- fused preprocessing: converts, bias concat, 7 weight transposes --
struct PrepArgs {
  const float* x; const float* xc;
  bf16* xbf; bf16* xcbf;
  const float* b4[4];   // bq,bk,bv,bcq
  const float* bc[2];   // bck,bcv
  float* bias4; float* biasc;
  const float* W[7];    // Wq,Wk,Wv,Wcq,Wp,Wck,Wcv
  bf16* WT[7];
};

__global__ __launch_bounds__(256) void prep_kernel(PrepArgs a) {
  __shared__ bf16 tsh[32][33];
  const int bx = blockIdx.x, tid = threadIdx.x;
  if (bx < 4096) {  // x fp32->bf16
    int i = bx * 256 + tid;
    float4 f = ((const float4*)a.x)[i];
    bf16 t[4] = {(bf16)f.x, (bf16)f.y, (bf16)f.z, (bf16)f.w};
    *(uint2*)&a.xbf[(long)i * 4] = *(const uint2*)t;
  } else if (bx < 4608) {  // xc fp32->bf16
    int i = (bx - 4096) * 256 + tid;
    float4 f = ((const float4*)a.xc)[i];
    bf16 t[4] = {(bf16)f.x, (bf16)f.y, (bf16)f.z, (bf16)f.w};
    *(uint2*)&a.xcbf[(long)i * 4] = *(const uint2*)t;
  } else if (bx < 4632) {  // bias concat
    int lb = bx - 4608;
    if (lb < 16) { int i = lb * 256 + tid; a.bias4[i] = a.b4[i >> 10][i & 1023]; }
    else         { int i = (lb - 16) * 256 + tid; a.biasc[i] = a.bc[i >> 10][i & 1023]; }
  } else {  // weight transpose [R,1024] fp32 -> [1024,R] bf16
    int t = bx - 4632, w, R, bxw, byw;
    if (t < 5120) { w = t >> 10; R = 1024; int l = t & 1023; bxw = l & 31; byw = l >> 5; }
    else { int t2 = t - 5120; w = 5 + (t2 >> 9); R = 512; int l = t2 & 511; bxw = l & 31; byw = l >> 5; }
    const float* in = a.W[w];
    bf16* out = a.WT[w];
    int tx = tid & 31, ty = tid >> 5;
    int c = bxw * 32 + tx;
#pragma unroll
    for (int i = 0; i < 4; i++) {
      int r = byw * 32 + ty + i * 8;
      tsh[ty + i * 8][tx] = (bf16)in[(long)r * 1024 + c];
    }
    __syncthreads();
    int oc = byw * 32 + tx;
#pragma unroll
    for (int i = 0; i < 4; i++) {
      int orr = bxw * 32 + ty + i * 8;
      out[(long)orr * R + oc] = tsh[tx][ty + i * 8];
    }
  }
}

// ---------------- 128x128 m97-style GEMM: C[M,N] = A[M,K] @ Bt[N,K]^T + bias -------
template <typename OutT>
__global__ __launch_bounds__(256, 3) void gemm128(const bf16* __restrict__ A,
                                                  const bf16* __restrict__ Bt,
                                                  const float* __restrict__ bias,
                                                  OutT* __restrict__ C,
                                                  int M, int N, int K, int ldc,
                                                  bf16* __restrict__ Vt,
                                                  int vcol0, int vcol1, int Lt, int tok_shift) {
  __shared__ alignas(16) bf16 As[128 * 32];
  __shared__ alignas(16) bf16 Bs[128 * 32];
  const int tid = threadIdx.x, wave = tid >> 6, lane = tid & 63;
  const int l16 = lane & 15, l4 = lane >> 4;
  const int wm = wave & 1, wn = wave >> 1;
  const int n0 = blockIdx.x * 128, m0 = blockIdx.y * 128;
  const int lrow = lane >> 2, lch = (lane & 3) * 8;

  floatx4 acc[4][4];
#pragma unroll
  for (int mt = 0; mt < 4; mt++)
#pragma unroll
    for (int nt = 0; nt < 4; nt++) acc[mt][nt] = (floatx4){0.f, 0.f, 0.f, 0.f};

  const bf16* Ag = A + (long)(m0 + wave * 32 + lrow) * K + lch;
  const bf16* Bg = Bt + (long)(n0 + wave * 32 + lrow) * K + lch;
  bf16* Al = &As[(wave * 32) * 32];
  bf16* Bl = &Bs[(wave * 32) * 32];

  for (int k0 = 0; k0 < K; k0 += 32) {
    __syncthreads();
    glds16(Ag + k0, Al);
    glds16(Ag + k0 + (long)16 * K, Al + 16 * 32);
    glds16(Bg + k0, Bl);
    glds16(Bg + k0 + (long)16 * K, Bl + 16 * 32);
    __syncthreads();
    bf16x8 a[4], b[4];
#pragma unroll
    for (int mt = 0; mt < 4; mt++) a[mt] = *(const bf16x8*)&As[(wm * 64 + mt * 16 + l16) * 32 + l4 * 8];
#pragma unroll
    for (int nt = 0; nt < 4; nt++) b[nt] = *(const bf16x8*)&Bs[(wn * 64 + nt * 16 + l16) * 32 + l4 * 8];
#pragma unroll
    for (int mt = 0; mt < 4; mt++)
#pragma unroll
      for (int nt = 0; nt < 4; nt++)
        acc[mt][nt] = __builtin_amdgcn_mfma_f32_16x16x32_bf16(a[mt], b[nt], acc[mt][nt], 0, 0, 0);
  }

  const bool vpath = (vcol0 >= 0) && (n0 >= vcol0) && (n0 < vcol1);
  if (!vpath) {
    const int coladj = (vcol0 >= 0 && n0 >= vcol1) ? (vcol1 - vcol0) : 0;
#pragma unroll
    for (int nt = 0; nt < 4; nt++) {
      int col = n0 + wn * 64 + nt * 16 + l16;
      float bv = bias[col];
#pragma unroll
      for (int mt = 0; mt < 4; mt++)
#pragma unroll
        for (int r = 0; r < 4; r++) {
          int row = m0 + wm * 64 + mt * 16 + l4 * 4 + r;
          float v = acc[mt][nt][r] + bv;
          if constexpr (std::is_same_v<OutT, float>) C[(long)row * ldc + col - coladj] = v;
          else                                       C[(long)row * ldc + col - coladj] = (bf16)v;
        }
    }
  } else {
#pragma unroll
    for (int nt = 0; nt < 4; nt++) {
      int col = n0 + wn * 64 + nt * 16 + l16;
      int c = col - vcol0, hh = c >> 6, dd = c & 63;
      float bv = bias[col];
#pragma unroll
      for (int mt = 0; mt < 4; mt++) {
        int t0 = m0 + wm * 64 + mt * 16 + l4 * 4;
        int bb = t0 >> tok_shift, t = t0 & ((1 << tok_shift) - 1);
        bf16 tmp[4];
#pragma unroll
        for (int r = 0; r < 4; r++) tmp[r] = (bf16)(acc[mt][nt][r] + bv);
        *(uint2*)&Vt[(((long)bb * 16 + hh) * 64 + dd) * Lt + t] = *(const uint2*)tmp;
      }
    }
  }
}

// ---------------- fused self(causal)+cross flash attention, S^T form ---------------
// grid (32, H, B), qt = 31-bx (heavy first). Computes S^T = K·Q^T (P in col-layout),
// then O^T = V^T·P^T with P^T B-fragments built via shuffles (no LDS round-trip).
__global__ __launch_bounds__(256, 3) void attn_kernel(const bf16* __restrict__ QKQc,
                                                      const bf16* __restrict__ VtB,
                                                      const bf16* __restrict__ KcB,
                                                      const bf16* __restrict__ VctB,
                                                      bf16* __restrict__ Y) {
  __shared__ alignas(16) bf16 Qs[64 * QLD];
  __shared__ alignas(16) bf16 Ks[128 * QLD];
  __shared__ alignas(16) bf16 Vts[64 * KLD];  // [d][key]
  const int tid = threadIdx.x, wave = tid >> 6, lane = tid & 63;
  const int l16 = lane & 15, l4 = lane >> 4;
  const int qt = 31 - (int)blockIdx.x, h = blockIdx.y, b = blockIdx.z;
  const int q0 = qt * 64;
  const int qa = q0 + wave * 16 + l16;  // this lane's query row (S^T column)

  float o_self[16];
  float m_i, l_i;
  floatx4 oacc[4];

  for (int phase = 0; phase < 2; phase++) {
    const bf16* Qb;
    const bf16* Kb;
    const bf16* Vtb;
    int kstr, vtstr, nkt;
    if (phase == 0) {
      Qb = QKQc + (long)b * 2048 * 3072 + h * 64;
      Kb = Qb + 1024;                              kstr = 3072;
      Vtb = VtB + ((long)b * 16 + h) * 64 * 2048;  vtstr = 2048;
      nkt = (qt + 2) >> 1;
    } else {
      Qb = QKQc + (long)b * 2048 * 3072 + h * 64 + 2048;
      Kb = KcB + (long)b * 512 * 1024 + h * 64;    kstr = 1024;
      Vtb = VctB + ((long)b * 16 + h) * 64 * 512;  vtstr = 512;
      nkt = 4;
    }

    __syncthreads();  // prior phase's LDS reads done
    // stage Q * (0.125*log2e) — exp2-form softmax
#pragma unroll
    for (int i = 0; i < 2; i++) {
      int idx = tid + i * 256, row = idx >> 3, ch = (idx & 7) * 8;
      bf16x8 qv = *(const bf16x8*)(Qb + (long)(q0 + row) * 3072 + ch);
#pragma unroll
      for (int j = 0; j < 8; j++) qv[j] = (bf16)((float)qv[j] * 0.18033688f);
      *(bf16x8*)&Qs[row * QLD + ch] = qv;
    }
    m_i = -__builtin_inff(); l_i = 0.f;
#pragma unroll
    for (int mt = 0; mt < 4; mt++) oacc[mt] = (floatx4){0.f, 0.f, 0.f, 0.f};

    // prefetch tile 0
    bf16x8 kreg[4], vreg[4];
#pragma unroll
    for (int c = 0; c < 4; c++) {
      int idx = tid + c * 256;
      kreg[c] = *(const bf16x8*)(Kb + (long)(idx >> 3) * kstr + (idx & 7) * 8);
      vreg[c] = *(const bf16x8*)(Vtb + (long)(idx >> 4) * vtstr + (idx & 15) * 8);
    }

    for (int kt = 0; kt < nkt; kt++) {
      const int k0 = kt * 128;
      __syncthreads();
#pragma unroll
      for (int c = 0; c < 4; c++) {
        int idx = tid + c * 256;
        *(bf16x8*)&Ks[(idx >> 3) * QLD + (idx & 7) * 8] = kreg[c];
        *(bf16x8*)&Vts[(idx >> 4) * KLD + (idx & 15) * 8] = vreg[c];
      }
      __syncthreads();
      if (kt + 1 < nkt) {
        const int kn = k0 + 128;
#pragma unroll
        for (int c = 0; c < 4; c++) {
          int idx = tid + c * 256;
          kreg[c] = *(const bf16x8*)(Kb + (long)(kn + (idx >> 3)) * kstr + (idx & 7) * 8);
          vreg[c] = *(const bf16x8*)(Vtb + (long)(idx >> 4) * vtstr + kn + (idx & 15) * 8);
        }
      }

      // S^T[key][q]: A = K rows, B = Q rows (as [d][q])
      floatx4 sacc[8];
#pragma unroll
      for (int mt = 0; mt < 8; mt++) sacc[mt] = (floatx4){0.f, 0.f, 0.f, 0.f};
#pragma unroll
      for (int ds = 0; ds < 2; ds++) {
        bf16x8 qf = *(const bf16x8*)&Qs[(wave * 16 + l16) * QLD + ds * 32 + l4 * 8];
#pragma unroll
        for (int mt = 0; mt < 8; mt++) {
          bf16x8 kf = *(const bf16x8*)&Ks[(mt * 16 + l16) * QLD + ds * 32 + l4 * 8];
          sacc[mt] = __builtin_amdgcn_mfma_f32_16x16x32_bf16(kf, qf, sacc[mt], 0, 0, 0);
        }
      }
      // causal mask (last self tile only): key = k0 + mt*16 + l4*4 + r
      if (phase == 0 && kt == nkt - 1) {
#pragma unroll
        for (int mt = 0; mt < 8; mt++) {
          int keyb = k0 + mt * 16 + l4 * 4;
#pragma unroll
          for (int r = 0; r < 4; r++)
            if (keyb + r > qa) sacc[mt][r] = -__builtin_inff();
        }
      }
      // online softmax (per-lane scalar state; reduce across quads: xor 16, 32)
      float mx = m_i;
#pragma unroll
      for (int mt = 0; mt < 8; mt++)
#pragma unroll
        for (int r = 0; r < 4; r++) mx = fmaxf(mx, sacc[mt][r]);
      mx = fmaxf(mx, __shfl_xor(mx, 16));
      mx = fmaxf(mx, __shfl_xor(mx, 32));
      float alpha = EXP2(m_i - mx);
      m_i = mx;
      float rs = 0.f;
      unsigned P2[8][2];
#pragma unroll
      for (int mt = 0; mt < 8; mt++) {
        float p0 = EXP2(sacc[mt][0] - mx), p1 = EXP2(sacc[mt][1] - mx);
        float p2 = EXP2(sacc[mt][2] - mx), p3 = EXP2(sacc[mt][3] - mx);
        rs += (p0 + p1) + (p2 + p3);
        P2[mt][0] = pack_bf16(p0, p1);
        P2[mt][1] = pack_bf16(p2, p3);
      }
      rs += __shfl_xor(rs, 16);
      rs += __shfl_xor(rs, 32);
      l_i = l_i * alpha + rs;
#pragma unroll
      for (int mt = 0; mt < 4; mt++)
#pragma unroll
        for (int r = 0; r < 4; r++) oacc[mt][r] *= alpha;

      // O^T += V^T · P^T : build P^T B-fragments via shuffles
      const int srcA = l16 | ((lane & 16) << 1);  // q + 32*(quad&1)
      const int srcB = srcA + 16;
      const bool hi = (lane & 32) != 0;           // quad>>1 selects mt pair
#pragma unroll
      for (int s = 0; s < 4; s++) {
        unsigned a0 = __shfl(P2[2 * s][0], srcA), b0 = __shfl(P2[2 * s + 1][0], srcA);
        unsigned a1 = __shfl(P2[2 * s][1], srcA), b1 = __shfl(P2[2 * s + 1][1], srcA);
        unsigned a2 = __shfl(P2[2 * s][0], srcB), b2 = __shfl(P2[2 * s + 1][0], srcB);
        unsigned a3 = __shfl(P2[2 * s][1], srcB), b3 = __shfl(P2[2 * s + 1][1], srcB);
        uint4 u;
        u.x = hi ? b0 : a0; u.y = hi ? b1 : a1; u.z = hi ? b2 : a2; u.w = hi ? b3 : a3;
        bf16x8 pf = __builtin_bit_cast(bf16x8, u);
#pragma unroll
        for (int mt = 0; mt < 4; mt++) {
          bf16x8 vf = *(const bf16x8*)&Vts[(mt * 16 + l16) * KLD + s * 32 + l4 * 8];
          oacc[mt] = __builtin_amdgcn_mfma_f32_16x16x32_bf16(vf, pf, oacc[mt], 0, 0, 0);
        }
      }
    }  // kt

    if (phase == 0) {
      float inv = 1.0f / l_i;
#pragma unroll
      for (int mt = 0; mt < 4; mt++)
#pragma unroll
        for (int r = 0; r < 4; r++) o_self[mt * 4 + r] = oacc[mt][r] * inv;
    } else {
      float inv = 1.0f / l_i;
      long row = (long)b * 2048 + qa;
#pragma unroll
      for (int mt = 0; mt < 4; mt++) {
        bf16 tmp[4];
#pragma unroll
        for (int r = 0; r < 4; r++) tmp[r] = (bf16)(o_self[mt * 4 + r] + oacc[mt][r] * inv);
        *(uint2*)&Y[row * 1024 + h * 64 + mt * 16 + l4 * 4] = *(const uint2*)tmp;
      }
    }
  }  // phase
}

extern "C" void kernel_launch(void* const* d_in, const int* in_sizes, int n_in,
                              void* d_out, int out_size, void* d_ws, size_t ws_size,
                              hipStream_t stream) {
  const float* x   = (const float*)d_in[0];
  const float* xc  = (const float*)d_in[1];
  const float* Wk  = (const float*)d_in[2];  const float* bk  = (const float*)d_in[3];
  const float* Wq  = (const float*)d_in[4];  const float* bq  = (const float*)d_in[5];
  const float* Wv  = (const float*)d_in[6];  const float* bv  = (const float*)d_in[7];
  const float* Wck = (const float*)d_in[8];  const float* bck = (const float*)d_in[9];
  const float* Wcq = (const float*)d_in[10]; const float* bcq = (const float*)d_in[11];
  const float* Wcv = (const float*)d_in[12]; const float* bcv = (const float*)d_in[13];
  const float* Wp  = (const float*)d_in[14]; const float* bp  = (const float*)d_in[15];

  char* ws = (char*)d_ws;
  const size_t MB = 1ull << 20;
  bf16*  WT_all = (bf16*)(ws + 0);         // [4096][1024]: Q|K|V|Qc
  bf16*  WC_all = (bf16*)(ws + 8 * MB);    // [2048][512]: Kc|Vc
  bf16*  WpT    = (bf16*)(ws + 10 * MB);   // [1024][1024]
  bf16*  xbf    = (bf16*)(ws + 12 * MB);   // [4096][1024]; Yb overlays after projections
  bf16*  Yb     = xbf;
  bf16*  xcbf   = (bf16*)(ws + 20 * MB);   // [1024][512]
  float* bias4  = (float*)(ws + 21 * MB);          // [4096]: bq|bk|bv|bcq
  float* biasc  = (float*)(ws + 21 * MB + 65536);  // [2048]: bck|bcv
  bf16*  QKQc   = (bf16*)(ws + 22 * MB);   // [4096][3072]: Q|K|Qc (compacted)
  bf16*  VtB    = (bf16*)(ws + 46 * MB);   // [2][16][64][2048]
  bf16*  KcB    = (bf16*)(ws + 54 * MB);   // [1024][1024]
  bf16*  VctB   = (bf16*)(ws + 56 * MB);   // [2][16][64][512]

  PrepArgs pa;
  pa.x = x; pa.xc = xc; pa.xbf = xbf; pa.xcbf = xcbf;
  pa.b4[0] = bq; pa.b4[1] = bk; pa.b4[2] = bv; pa.b4[3] = bcq;
  pa.bc[0] = bck; pa.bc[1] = bcv;
  pa.bias4 = bias4; pa.biasc = biasc;
  pa.W[0] = Wq;  pa.WT[0] = WT_all + 0ll * 1024 * 1024;
  pa.W[1] = Wk;  pa.WT[1] = WT_all + 1ll * 1024 * 1024;
  pa.W[2] = Wv;  pa.WT[2] = WT_all + 2ll * 1024 * 1024;
  pa.W[3] = Wcq; pa.WT[3] = WT_all + 3ll * 1024 * 1024;
  pa.W[4] = Wp;  pa.WT[4] = WpT;
  pa.W[5] = Wck; pa.WT[5] = WC_all + 0ll * 1024 * 512;
  pa.W[6] = Wcv; pa.WT[6] = WC_all + 1ll * 1024 * 512;
  prep_kernel<<<10776, 256, 0, stream>>>(pa);

  // fused QKV+Qc projection: N=4096; V section [2048,3072) -> VtB transposed
  gemm128<bf16><<<dim3(32, 32), 256, 0, stream>>>(xbf, WT_all, bias4, QKQc,
                                                  4096, 4096, 1024, 3072,
                                                  VtB, 2048, 3072, 2048, 11);
  // fused cross K+V: N=2048; Vc section [1024,2048) -> VctB transposed
  gemm128<bf16><<<dim3(16, 8), 256, 0, stream>>>(xcbf, WC_all, biasc, KcB,
                                                 1024, 2048, 512, 1024,
                                                 VctB, 1024, 2048, 512, 9);

  attn_kernel<<<dim3(32, 16, 2), 256, 0, stream>>>(QKQc, VtB, KcB, VctB, Yb);

  gemm128<float><<<dim3(8, 32), 256, 0, stream>>>(Yb, WpT, bp, (float*)d_out,
                                                  4096, 1024, 1024, 1024,
                                                  nullptr, -1, -1, 0, 0);
}

// Round 5
// 288.617 us; speedup vs baseline: 1.0483x; 1.0483x over previous
//
#include <hip/hip_runtime.h>
#include <hip/hip_bf16.h>
#include <type_traits>

typedef __bf16 bf16;
typedef __bf16 bf16x8 __attribute__((ext_vector_type(8)));
typedef float floatx4 __attribute__((ext_vector_type(4)));

#define QLD 72    // K-tile row: 64 d + 8 pad (144 B, 16B-aligned)
#define KLD 136   // V^T/P row: 128 keys + 8 pad (272 B, 16B-aligned)

#if __has_builtin(__builtin_amdgcn_exp2f)
#define EXP2(x) __builtin_amdgcn_exp2f(x)
#else
#define EXP2(x) exp2f(x)
#endif

__device__ __forceinline__ void glds16(const bf16* g, bf16* l) {
  __builtin_amdgcn_global_load_lds((const __attribute__((address_space(1))) void*)g,
                                   (__attribute__((address_space(3))) void*)l, 16, 0, 0);
}

// ---------------- fused preprocessing: converts, bias concat, 7 weight transposes --
struct PrepArgs {
  const float* x; const float* xc;
  bf16* xbf; bf16* xcbf;
  const float* b4[4];   // bq,bk,bv,bcq
  const float* bc[2];   // bck,bcv
  float* bias4; float* biasc;
  const float* W[7];    // Wq,Wk,Wv,Wcq,Wp,Wck,Wcv
  bf16* WT[7];
};

__global__ __launch_bounds__(256) void prep_kernel(PrepArgs a) {
  __shared__ bf16 tsh[32][33];
  const int bx = blockIdx.x, tid = threadIdx.x;
  if (bx < 4096) {  // x fp32->bf16
    int i = bx * 256 + tid;
    float4 f = ((const float4*)a.x)[i];
    bf16 t[4] = {(bf16)f.x, (bf16)f.y, (bf16)f.z, (bf16)f.w};
    *(uint2*)&a.xbf[(long)i * 4] = *(const uint2*)t;
  } else if (bx < 4608) {  // xc fp32->bf16
    int i = (bx - 4096) * 256 + tid;
    float4 f = ((const float4*)a.xc)[i];
    bf16 t[4] = {(bf16)f.x, (bf16)f.y, (bf16)f.z, (bf16)f.w};
    *(uint2*)&a.xcbf[(long)i * 4] = *(const uint2*)t;
  } else if (bx < 4632) {  // bias concat
    int lb = bx - 4608;
    if (lb < 16) { int i = lb * 256 + tid; a.bias4[i] = a.b4[i >> 10][i & 1023]; }
    else         { int i = (lb - 16) * 256 + tid; a.biasc[i] = a.bc[i >> 10][i & 1023]; }
  } else {  // weight transpose [R,1024] fp32 -> [1024,R] bf16
    int t = bx - 4632, w, R, bxw, byw;
    if (t < 5120) { w = t >> 10; R = 1024; int l = t & 1023; bxw = l & 31; byw = l >> 5; }
    else { int t2 = t - 5120; w = 5 + (t2 >> 9); R = 512; int l = t2 & 511; bxw = l & 31; byw = l >> 5; }
    const float* in = a.W[w];
    bf16* out = a.WT[w];
    int tx = tid & 31, ty = tid >> 5;
    int c = bxw * 32 + tx;
#pragma unroll
    for (int i = 0; i < 4; i++) {
      int r = byw * 32 + ty + i * 8;
      tsh[ty + i * 8][tx] = (bf16)in[(long)r * 1024 + c];
    }
    __syncthreads();
    int oc = byw * 32 + tx;
#pragma unroll
    for (int i = 0; i < 4; i++) {
      int orr = bxw * 32 + ty + i * 8;
      out[(long)orr * R + oc] = tsh[tx][ty + i * 8];
    }
  }
}

// ---------------- 128x128 m97-style GEMM: C[M,N] = A[M,K] @ Bt[N,K]^T + bias -------
template <typename OutT>
__global__ __launch_bounds__(256, 3) void gemm128(const bf16* __restrict__ A,
                                                  const bf16* __restrict__ Bt,
                                                  const float* __restrict__ bias,
                                                  OutT* __restrict__ C,
                                                  int M, int N, int K, int ldc,
                                                  bf16* __restrict__ Vt,
                                                  int vcol0, int vcol1, int Lt, int tok_shift) {
  __shared__ alignas(16) bf16 As[128 * 32];
  __shared__ alignas(16) bf16 Bs[128 * 32];
  const int tid = threadIdx.x, wave = tid >> 6, lane = tid & 63;
  const int l16 = lane & 15, l4 = lane >> 4;
  const int wm = wave & 1, wn = wave >> 1;
  const int n0 = blockIdx.x * 128, m0 = blockIdx.y * 128;
  const int lrow = lane >> 2, lch = (lane & 3) * 8;

  floatx4 acc[4][4];
#pragma unroll
  for (int mt = 0; mt < 4; mt++)
#pragma unroll
    for (int nt = 0; nt < 4; nt++) acc[mt][nt] = (floatx4){0.f, 0.f, 0.f, 0.f};

  const bf16* Ag = A + (long)(m0 + wave * 32 + lrow) * K + lch;
  const bf16* Bg = Bt + (long)(n0 + wave * 32 + lrow) * K + lch;
  bf16* Al = &As[(wave * 32) * 32];
  bf16* Bl = &Bs[(wave * 32) * 32];

  for (int k0 = 0; k0 < K; k0 += 32) {
    __syncthreads();
    glds16(Ag + k0, Al);
    glds16(Ag + k0 + (long)16 * K, Al + 16 * 32);
    glds16(Bg + k0, Bl);
    glds16(Bg + k0 + (long)16 * K, Bl + 16 * 32);
    __syncthreads();
    bf16x8 a[4], b[4];
#pragma unroll
    for (int mt = 0; mt < 4; mt++) a[mt] = *(const bf16x8*)&As[(wm * 64 + mt * 16 + l16) * 32 + l4 * 8];
#pragma unroll
    for (int nt = 0; nt < 4; nt++) b[nt] = *(const bf16x8*)&Bs[(wn * 64 + nt * 16 + l16) * 32 + l4 * 8];
#pragma unroll
    for (int mt = 0; mt < 4; mt++)
#pragma unroll
      for (int nt = 0; nt < 4; nt++)
        acc[mt][nt] = __builtin_amdgcn_mfma_f32_16x16x32_bf16(a[mt], b[nt], acc[mt][nt], 0, 0, 0);
  }

  const bool vpath = (vcol0 >= 0) && (n0 >= vcol0) && (n0 < vcol1);
  if (!vpath) {
    const int coladj = (vcol0 >= 0 && n0 >= vcol1) ? (vcol1 - vcol0) : 0;
#pragma unroll
    for (int nt = 0; nt < 4; nt++) {
      int col = n0 + wn * 64 + nt * 16 + l16;
      float bv = bias[col];
#pragma unroll
      for (int mt = 0; mt < 4; mt++)
#pragma unroll
        for (int r = 0; r < 4; r++) {
          int row = m0 + wm * 64 + mt * 16 + l4 * 4 + r;
          float v = acc[mt][nt][r] + bv;
          if constexpr (std::is_same_v<OutT, float>) C[(long)row * ldc + col - coladj] = v;
          else                                       C[(long)row * ldc + col - coladj] = (bf16)v;
        }
    }
  } else {
#pragma unroll
    for (int nt = 0; nt < 4; nt++) {
      int col = n0 + wn * 64 + nt * 16 + l16;
      int c = col - vcol0, hh = c >> 6, dd = c & 63;
      float bv = bias[col];
#pragma unroll
      for (int mt = 0; mt < 4; mt++) {
        int t0 = m0 + wm * 64 + mt * 16 + l4 * 4;
        int bb = t0 >> tok_shift, t = t0 & ((1 << tok_shift) - 1);
        bf16 tmp[4];
#pragma unroll
        for (int r = 0; r < 4; r++) tmp[r] = (bf16)(acc[mt][nt][r] + bv);
        *(uint2*)&Vt[(((long)bb * 16 + hh) * 64 + dd) * Lt + t] = *(const uint2*)tmp;
      }
    }
  }
}

// ---------------- fused self(causal)+cross flash attention (round-3 S-form) --------
// grid (16, H, B): block does q-tiles {bx, 31-bx} (uniform 25 k-iters). Q fragments
// live in registers (no LDS); LDS = Ks + Vts + Ps = 52 KB -> 3 blocks/CU.
__global__ __launch_bounds__(256, 3) void attn_kernel(const bf16* __restrict__ QKQc,
                                                      const bf16* __restrict__ VtB,
                                                      const bf16* __restrict__ KcB,
                                                      const bf16* __restrict__ VctB,
                                                      bf16* __restrict__ Y) {
  __shared__ alignas(16) bf16 Ks[128 * QLD];
  __shared__ alignas(16) bf16 Vts[64 * KLD];   // [d][key]
  __shared__ alignas(16) bf16 Ps[64 * KLD];    // [q][key]
  const int tid = threadIdx.x, wave = tid >> 6, lane = tid & 63;
  const int l16 = lane & 15, l4 = lane >> 4;
  const int h = blockIdx.y, b = blockIdx.z;

  float o_self[4][4];
  float m_i[4], l_i[4];
  floatx4 oacc[4];

  for (int jj = 0; jj < 2; jj++) {
    const int qt = jj ? (31 - (int)blockIdx.x) : (int)blockIdx.x;
    const int q0 = qt * 64;
    const int qrow0 = q0 + wave * 16 + l4 * 4;

    for (int phase = 0; phase < 2; phase++) {
      const bf16* Qb;
      const bf16* Kb;
      const bf16* Vtb;
      int kstr, vtstr, nkt;
      if (phase == 0) {
        Qb = QKQc + (long)b * 2048 * 3072 + h * 64;
        Kb = Qb + 1024;                              kstr = 3072;
        Vtb = VtB + ((long)b * 16 + h) * 64 * 2048;  vtstr = 2048;
        nkt = (qt + 2) >> 1;
      } else {
        Qb = QKQc + (long)b * 2048 * 3072 + h * 64 + 2048;
        Kb = KcB + (long)b * 512 * 1024 + h * 64;    kstr = 1024;
        Vtb = VctB + ((long)b * 16 + h) * 64 * 512;  vtstr = 512;
        nkt = 4;
      }

      // Q A-fragment straight from global into registers, scale*log2e folded in
      bf16x8 qf[2];
      {
        const bf16* qp = Qb + (long)(q0 + wave * 16 + l16) * 3072 + l4 * 8;
#pragma unroll
        for (int ds = 0; ds < 2; ds++) {
          bf16x8 v = *(const bf16x8*)(qp + ds * 32);
#pragma unroll
          for (int j = 0; j < 8; j++) v[j] = (bf16)((float)v[j] * 0.18033688f);
          qf[ds] = v;
        }
      }
#pragma unroll
      for (int r = 0; r < 4; r++) { m_i[r] = -__builtin_inff(); l_i[r] = 0.f; }
#pragma unroll
      for (int nt = 0; nt < 4; nt++) oacc[nt] = (floatx4){0.f, 0.f, 0.f, 0.f};

      // prefetch tile 0
      bf16x8 kreg[4], vreg[4];
#pragma unroll
      for (int c = 0; c < 4; c++) {
        int idx = tid + c * 256;
        kreg[c] = *(const bf16x8*)(Kb + (long)(idx >> 3) * kstr + (idx & 7) * 8);
        vreg[c] = *(const bf16x8*)(Vtb + (long)(idx >> 4) * vtstr + (idx & 15) * 8);
      }

      for (int kt = 0; kt < nkt; kt++) {
        const int k0 = kt * 128;
        __syncthreads();  // prior-iter (and prior-phase) LDS reads done
#pragma unroll
        for (int c = 0; c < 4; c++) {
          int idx = tid + c * 256;
          *(bf16x8*)&Ks[(idx >> 3) * QLD + (idx & 7) * 8] = kreg[c];
          *(bf16x8*)&Vts[(idx >> 4) * KLD + (idx & 15) * 8] = vreg[c];
        }
        __syncthreads();
        if (kt + 1 < nkt) {  // prefetch next tile
          const int kn = k0 + 128;
#pragma unroll
          for (int c = 0; c < 4; c++) {
            int idx = tid + c * 256;
            kreg[c] = *(const bf16x8*)(Kb + (long)(kn + (idx >> 3)) * kstr + (idx & 7) * 8);
            vreg[c] = *(const bf16x8*)(Vtb + (long)(idx >> 4) * vtstr + kn + (idx & 15) * 8);
          }
        }

        // S = Q K^T : 64q x 128k (Q from registers)
        floatx4 sacc[8];
#pragma unroll
        for (int nt = 0; nt < 8; nt++) sacc[nt] = (floatx4){0.f, 0.f, 0.f, 0.f};
#pragma unroll
        for (int ds = 0; ds < 2; ds++) {
#pragma unroll
          for (int nt = 0; nt < 8; nt++) {
            bf16x8 bfr = *(const bf16x8*)&Ks[(nt * 16 + l16) * QLD + ds * 32 + l4 * 8];
            sacc[nt] = __builtin_amdgcn_mfma_f32_16x16x32_bf16(qf[ds], bfr, sacc[nt], 0, 0, 0);
          }
        }
        // causal mask: only the last self tile straddles the diagonal
        if (phase == 0 && kt == nkt - 1) {
          int keyb = k0 + l16;
#pragma unroll
          for (int nt = 0; nt < 8; nt++) {
            int key = keyb + nt * 16;
#pragma unroll
            for (int r = 0; r < 4; r++)
              if (key > qrow0 + r) sacc[nt][r] = -__builtin_inff();
          }
        }
        // online softmax (exp2 form; reduce over l16: xor 1,2,4,8)
        float mx[4];
#pragma unroll
        for (int r = 0; r < 4; r++) mx[r] = m_i[r];
#pragma unroll
        for (int nt = 0; nt < 8; nt++)
#pragma unroll
          for (int r = 0; r < 4; r++) mx[r] = fmaxf(mx[r], sacc[nt][r]);
#pragma unroll
        for (int r = 0; r < 4; r++) {
#pragma unroll
          for (int off = 1; off < 16; off <<= 1) mx[r] = fmaxf(mx[r], __shfl_xor(mx[r], off));
        }
        float alpha[4], rs[4];
#pragma unroll
        for (int r = 0; r < 4; r++) {
          alpha[r] = EXP2(m_i[r] - mx[r]);
          m_i[r] = mx[r];
          rs[r] = 0.f;
        }
#pragma unroll
        for (int nt = 0; nt < 8; nt++)
#pragma unroll
          for (int r = 0; r < 4; r++) {
            float p = EXP2(sacc[nt][r] - mx[r]);
            rs[r] += p;
            Ps[(wave * 16 + l4 * 4 + r) * KLD + nt * 16 + l16] = (bf16)p;
          }
#pragma unroll
        for (int r = 0; r < 4; r++) {
#pragma unroll
          for (int off = 1; off < 16; off <<= 1) rs[r] += __shfl_xor(rs[r], off);
          l_i[r] = l_i[r] * alpha[r] + rs[r];
        }
#pragma unroll
        for (int nt = 0; nt < 4; nt++)
#pragma unroll
          for (int r = 0; r < 4; r++) oacc[nt][r] *= alpha[r];
        // O += P V  (wave-private P rows; lgkmcnt ordering, no barrier)
#pragma unroll
        for (int ks = 0; ks < 4; ks++) {
          bf16x8 af = *(const bf16x8*)&Ps[(wave * 16 + l16) * KLD + ks * 32 + l4 * 8];
#pragma unroll
          for (int nt = 0; nt < 4; nt++) {
            bf16x8 bfr = *(const bf16x8*)&Vts[(nt * 16 + l16) * KLD + ks * 32 + l4 * 8];
            oacc[nt] = __builtin_amdgcn_mfma_f32_16x16x32_bf16(af, bfr, oacc[nt], 0, 0, 0);
          }
        }
      }  // kt

      if (phase == 0) {
#pragma unroll
        for (int r = 0; r < 4; r++) {
          float inv = 1.0f / l_i[r];
#pragma unroll
          for (int nt = 0; nt < 4; nt++) o_self[nt][r] = oacc[nt][r] * inv;
        }
      } else {
#pragma unroll
        for (int r = 0; r < 4; r++) {
          float inv = 1.0f / l_i[r];
          long row = (long)b * 2048 + qrow0 + r;
#pragma unroll
          for (int nt = 0; nt < 4; nt++) {
            int col = h * 64 + nt * 16 + l16;
            Y[row * 1024 + col] = (bf16)(o_self[nt][r] + oacc[nt][r] * inv);
          }
        }
      }
    }  // phase
  }  // jj
}

extern "C" void kernel_launch(void* const* d_in, const int* in_sizes, int n_in,
                              void* d_out, int out_size, void* d_ws, size_t ws_size,
                              hipStream_t stream) {
  const float* x   = (const float*)d_in[0];
  const float* xc  = (const float*)d_in[1];
  const float* Wk  = (const float*)d_in[2];  const float* bk  = (const float*)d_in[3];
  const float* Wq  = (const float*)d_in[4];  const float* bq  = (const float*)d_in[5];
  const float* Wv  = (const float*)d_in[6];  const float* bv  = (const float*)d_in[7];
  const float* Wck = (const float*)d_in[8];  const float* bck = (const float*)d_in[9];
  const float* Wcq = (const float*)d_in[10]; const float* bcq = (const float*)d_in[11];
  const float* Wcv = (const float*)d_in[12]; const float* bcv = (const float*)d_in[13];
  const float* Wp  = (const float*)d_in[14]; const float* bp  = (const float*)d_in[15];

  char* ws = (char*)d_ws;
  const size_t MB = 1ull << 20;
  bf16*  WT_all = (bf16*)(ws + 0);         // [4096][1024]: Q|K|V|Qc
  bf16*  WC_all = (bf16*)(ws + 8 * MB);    // [2048][512]: Kc|Vc
  bf16*  WpT    = (bf16*)(ws + 10 * MB);   // [1024][1024]
  bf16*  xbf    = (bf16*)(ws + 12 * MB);   // [4096][1024]; Yb overlays after projections
  bf16*  Yb     = xbf;
  bf16*  xcbf   = (bf16*)(ws + 20 * MB);   // [1024][512]
  float* bias4  = (float*)(ws + 21 * MB);          // [4096]: bq|bk|bv|bcq
  float* biasc  = (float*)(ws + 21 * MB + 65536);  // [2048]: bck|bcv
  bf16*  QKQc   = (bf16*)(ws + 22 * MB);   // [4096][3072]: Q|K|Qc (compacted)
  bf16*  VtB    = (bf16*)(ws + 46 * MB);   // [2][16][64][2048]
  bf16*  KcB    = (bf16*)(ws + 54 * MB);   // [1024][1024]
  bf16*  VctB   = (bf16*)(ws + 56 * MB);   // [2][16][64][512]

  PrepArgs pa;
  pa.x = x; pa.xc = xc; pa.xbf = xbf; pa.xcbf = xcbf;
  pa.b4[0] = bq; pa.b4[1] = bk; pa.b4[2] = bv; pa.b4[3] = bcq;
  pa.bc[0] = bck; pa.bc[1] = bcv;
  pa.bias4 = bias4; pa.biasc = biasc;
  pa.W[0] = Wq;  pa.WT[0] = WT_all + 0ll * 1024 * 1024;
  pa.W[1] = Wk;  pa.WT[1] = WT_all + 1ll * 1024 * 1024;
  pa.W[2] = Wv;  pa.WT[2] = WT_all + 2ll * 1024 * 1024;
  pa.W[3] = Wcq; pa.WT[3] = WT_all + 3ll * 1024 * 1024;
  pa.W[4] = Wp;  pa.WT[4] = WpT;
  pa.W[5] = Wck; pa.WT[5] = WC_all + 0ll * 1024 * 512;
  pa.W[6] = Wcv; pa.WT[6] = WC_all + 1ll * 1024 * 512;
  prep_kernel<<<10776, 256, 0, stream>>>(pa);

  // fused QKV+Qc projection: N=4096; V section [2048,3072) -> VtB transposed
  gemm128<bf16><<<dim3(32, 32), 256, 0, stream>>>(xbf, WT_all, bias4, QKQc,
                                                  4096, 4096, 1024, 3072,
                                                  VtB, 2048, 3072, 2048, 11);
  // fused cross K+V: N=2048; Vc section [1024,2048) -> VctB transposed
  gemm128<bf16><<<dim3(16, 8), 256, 0, stream>>>(xcbf, WC_all, biasc, KcB,
                                                 1024, 2048, 512, 1024,
                                                 VctB, 1024, 2048, 512, 9);

  attn_kernel<<<dim3(16, 16, 2), 256, 0, stream>>>(QKQc, VtB, KcB, VctB, Yb);

  gemm128<float><<<dim3(8, 32), 256, 0, stream>>>(Yb, WpT, bp, (float*)d_out,
                                                  4096, 1024, 1024, 1024,
                                                  nullptr, -1, -1, 0, 0);
}

// Round 6
// 260.866 us; speedup vs baseline: 1.1598x; 1.1064x over previous
//
#include <hip/hip_runtime.h>
#include <hip/hip_bf16.h>
#include <type_traits>

typedef __bf16 bf16;
typedef __bf16 bf16x8 __attribute__((ext_vector_type(8)));
typedef float floatx4 __attribute__((ext_vector_type(4)));

#if __has_builtin(__builtin_amdgcn_exp2f)
#define EXP2(x) __builtin_amdgcn_exp2f(x)
#else
#define EXP2(x) exp2f(x)
#endif

__device__ __forceinline__ void glds16(const bf16* g, bf16* l) {
  __builtin_amdgcn_global_load_lds((const __attribute__((address_space(1))) void*)g,
                                   (__attribute__((address_space(3))) void*)l, 16, 0, 0);
}

__device__ __forceinline__ unsigned pack_bf16(float a, float b) {
  unsigned short ua = __builtin_bit_cast(unsigned short, (bf16)a);
  unsigned short ub = __builtin_bit_cast(unsigned short, (bf16)b);
  return (unsigned)ua | ((unsigned)ub << 16);
}

// ---------------- fused preprocessing: converts, bias concat, 7 weight transposes --
struct PrepArgs {
  const float* x; const float* xc;
  bf16* xbf; bf16* xcbf;
  const float* b4[4];   // bq,bk,bv,bcq
  const float* bc[2];   // bck,bcv
  float* bias4; float* biasc;
  const float* W[7];    // Wq,Wk,Wv,Wcq,Wp,Wck,Wcv
  bf16* WT[7];
};

__global__ __launch_bounds__(256) void prep_kernel(PrepArgs a) {
  __shared__ bf16 tsh[32][33];
  const int bx = blockIdx.x, tid = threadIdx.x;
  if (bx < 4096) {  // x fp32->bf16
    int i = bx * 256 + tid;
    float4 f = ((const float4*)a.x)[i];
    bf16 t[4] = {(bf16)f.x, (bf16)f.y, (bf16)f.z, (bf16)f.w};
    *(uint2*)&a.xbf[(long)i * 4] = *(const uint2*)t;
  } else if (bx < 4608) {  // xc fp32->bf16
    int i = (bx - 4096) * 256 + tid;
    float4 f = ((const float4*)a.xc)[i];
    bf16 t[4] = {(bf16)f.x, (bf16)f.y, (bf16)f.z, (bf16)f.w};
    *(uint2*)&a.xcbf[(long)i * 4] = *(const uint2*)t;
  } else if (bx < 4632) {  // bias concat
    int lb = bx - 4608;
    if (lb < 16) { int i = lb * 256 + tid; a.bias4[i] = a.b4[i >> 10][i & 1023]; }
    else         { int i = (lb - 16) * 256 + tid; a.biasc[i] = a.bc[i >> 10][i & 1023]; }
  } else {  // weight transpose [R,1024] fp32 -> [1024,R] bf16
    int t = bx - 4632, w, R, bxw, byw;
    if (t < 5120) { w = t >> 10; R = 1024; int l = t & 1023; bxw = l & 31; byw = l >> 5; }
    else { int t2 = t - 5120; w = 5 + (t2 >> 9); R = 512; int l = t2 & 511; bxw = l & 31; byw = l >> 5; }
    const float* in = a.W[w];
    bf16* out = a.WT[w];
    int tx = tid & 31, ty = tid >> 5;
    int c = bxw * 32 + tx;
#pragma unroll
    for (int i = 0; i < 4; i++) {
      int r = byw * 32 + ty + i * 8;
      tsh[ty + i * 8][tx] = (bf16)in[(long)r * 1024 + c];
    }
    __syncthreads();
    int oc = byw * 32 + tx;
#pragma unroll
    for (int i = 0; i < 4; i++) {
      int orr = bxw * 32 + ty + i * 8;
      out[(long)orr * R + oc] = tsh[tx][ty + i * 8];
    }
  }
}

// ---------------- 128x128 m97-style GEMM: C[M,N] = A[M,K] @ Bt[N,K]^T + bias -------
template <typename OutT>
__global__ __launch_bounds__(256, 3) void gemm128(const bf16* __restrict__ A,
                                                  const bf16* __restrict__ Bt,
                                                  const float* __restrict__ bias,
                                                  OutT* __restrict__ C,
                                                  int M, int N, int K, int ldc,
                                                  bf16* __restrict__ Vt,
                                                  int vcol0, int vcol1, int Lt, int tok_shift) {
  __shared__ alignas(16) bf16 As[128 * 32];
  __shared__ alignas(16) bf16 Bs[128 * 32];
  const int tid = threadIdx.x, wave = tid >> 6, lane = tid & 63;
  const int l16 = lane & 15, l4 = lane >> 4;
  const int wm = wave & 1, wn = wave >> 1;
  const int n0 = blockIdx.x * 128, m0 = blockIdx.y * 128;
  const int lrow = lane >> 2, lch = (lane & 3) * 8;

  floatx4 acc[4][4];
#pragma unroll
  for (int mt = 0; mt < 4; mt++)
#pragma unroll
    for (int nt = 0; nt < 4; nt++) acc[mt][nt] = (floatx4){0.f, 0.f, 0.f, 0.f};

  const bf16* Ag = A + (long)(m0 + wave * 32 + lrow) * K + lch;
  const bf16* Bg = Bt + (long)(n0 + wave * 32 + lrow) * K + lch;
  bf16* Al = &As[(wave * 32) * 32];
  bf16* Bl = &Bs[(wave * 32) * 32];

  for (int k0 = 0; k0 < K; k0 += 32) {
    __syncthreads();
    glds16(Ag + k0, Al);
    glds16(Ag + k0 + (long)16 * K, Al + 16 * 32);
    glds16(Bg + k0, Bl);
    glds16(Bg + k0 + (long)16 * K, Bl + 16 * 32);
    __syncthreads();
    bf16x8 a[4], b[4];
#pragma unroll
    for (int mt = 0; mt < 4; mt++) a[mt] = *(const bf16x8*)&As[(wm * 64 + mt * 16 + l16) * 32 + l4 * 8];
#pragma unroll
    for (int nt = 0; nt < 4; nt++) b[nt] = *(const bf16x8*)&Bs[(wn * 64 + nt * 16 + l16) * 32 + l4 * 8];
#pragma unroll
    for (int mt = 0; mt < 4; mt++)
#pragma unroll
      for (int nt = 0; nt < 4; nt++)
        acc[mt][nt] = __builtin_amdgcn_mfma_f32_16x16x32_bf16(a[mt], b[nt], acc[mt][nt], 0, 0, 0);
  }

  const bool vpath = (vcol0 >= 0) && (n0 >= vcol0) && (n0 < vcol1);
  if (!vpath) {
    const int coladj = (vcol0 >= 0 && n0 >= vcol1) ? (vcol1 - vcol0) : 0;
#pragma unroll
    for (int nt = 0; nt < 4; nt++) {
      int col = n0 + wn * 64 + nt * 16 + l16;
      float bv = bias[col];
#pragma unroll
      for (int mt = 0; mt < 4; mt++)
#pragma unroll
        for (int r = 0; r < 4; r++) {
          int row = m0 + wm * 64 + mt * 16 + l4 * 4 + r;
          float v = acc[mt][nt][r] + bv;
          if constexpr (std::is_same_v<OutT, float>) C[(long)row * ldc + col - coladj] = v;
          else                                       C[(long)row * ldc + col - coladj] = (bf16)v;
        }
    }
  } else {
#pragma unroll
    for (int nt = 0; nt < 4; nt++) {
      int col = n0 + wn * 64 + nt * 16 + l16;
      int c = col - vcol0, hh = c >> 6, dd = c & 63;
      float bv = bias[col];
#pragma unroll
      for (int mt = 0; mt < 4; mt++) {
        int t0 = m0 + wm * 64 + mt * 16 + l4 * 4;
        int bb = t0 >> tok_shift, t = t0 & ((1 << tok_shift) - 1);
        bf16 tmp[4];
#pragma unroll
        for (int r = 0; r < 4; r++) tmp[r] = (bf16)(acc[mt][nt][r] + bv);
        *(uint2*)&Vt[(((long)bb * 16 + hh) * 64 + dd) * Lt + t] = *(const uint2*)tmp;
      }
    }
  }
}

// ---------------- barrier-free fused self(causal)+cross flash attention ------------
// grid (32 bh, 32 qt'): qt = 31-qt' (heavy first); bh-major => same (b,h) on one XCD.
// Keys striped across waves (wave w owns keys [w*32,w*32+32) of each 128-tile);
// each wave runs independent online softmax; flash-combine across waves once/phase.
// K/V^T/Q all global->register; P^T round-trips a wave-private LDS slab.
__global__ __launch_bounds__(256, 2) void attn_kernel(const bf16* __restrict__ QKQc,
                                                      const bf16* __restrict__ VtB,
                                                      const bf16* __restrict__ KcB,
                                                      const bf16* __restrict__ VctB,
                                                      bf16* __restrict__ Y) {
  __shared__ float2 Mbuf[4][4][16];          // [wave][qt][l16] = (m, l)
  __shared__ alignas(16) bf16 U[4 * 64 * 72]; // union: Pbuf [w][64q][48k] / Obuf [s][64q][72d]
  const int tid = threadIdx.x, w = tid >> 6, lane = tid & 63;
  const int l16 = lane & 15, l4 = lane >> 4;
  const int bh = blockIdx.x, h = bh & 15, b = bh >> 4;
  const int qt = 31 - (int)blockIdx.y;
  const int q0 = qt * 64;
  const int wk = w * 32;                     // wave's key offset inside a 128-tile
  bf16* Pw = U + w * (64 * 48);
  const float NEG = -1e30f;

  float o_self[16];

  for (int phase = 0; phase < 2; phase++) {
    const bf16 *Qb, *Kb, *Vtb;
    int kstr, vtstr, nkt;
    if (phase == 0) {
      Qb = QKQc + (long)b * 2048 * 3072 + h * 64;
      Kb = Qb + 1024;                              kstr = 3072;
      Vtb = VtB + ((long)b * 16 + h) * 64 * 2048;  vtstr = 2048;
      nkt = (qt + 2) >> 1;
    } else {
      Qb = QKQc + (long)b * 2048 * 3072 + h * 64 + 2048;
      Kb = KcB + (long)b * 512 * 1024 + h * 64;    kstr = 1024;
      Vtb = VctB + ((long)b * 16 + h) * 64 * 512;  vtstr = 512;
      nkt = 4;
    }

    __syncthreads();  // Pbuf/Obuf/Mbuf safe to reuse across phases

    // Q B-frags for the whole phase (scale*log2e folded in)
    bf16x8 qf[4][2];
#pragma unroll
    for (int qtt = 0; qtt < 4; qtt++) {
      const bf16* qp = Qb + (long)(q0 + qtt * 16 + l16) * 3072 + l4 * 8;
#pragma unroll
      for (int ds = 0; ds < 2; ds++) {
        bf16x8 v = *(const bf16x8*)(qp + ds * 32);
#pragma unroll
        for (int j = 0; j < 8; j++) v[j] = (bf16)((float)v[j] * 0.18033688f);
        qf[qtt][ds] = v;
      }
    }

    float m_i[4], l_i[4];
#pragma unroll
    for (int qtt = 0; qtt < 4; qtt++) { m_i[qtt] = NEG; l_i[qtt] = 0.f; }
    floatx4 oacc[4][4];  // [mtd (d)][qt]: O^T accumulation
#pragma unroll
    for (int mtd = 0; mtd < 4; mtd++)
#pragma unroll
      for (int qtt = 0; qtt < 4; qtt++) oacc[mtd][qtt] = (floatx4){0.f, 0.f, 0.f, 0.f};

    // prefetch K tile 0 (wave's own 32 keys)
    bf16x8 kc[2][2], kn[2][2];
#pragma unroll
    for (int mt = 0; mt < 2; mt++)
#pragma unroll
      for (int ds = 0; ds < 2; ds++)
        kc[mt][ds] = *(const bf16x8*)(Kb + (long)(wk + mt * 16 + l16) * kstr + ds * 32 + l4 * 8);

    for (int kt = 0; kt < nkt; kt++) {
      const int kbase = kt * 128 + wk;
      // V^T for this tile (consumed at the end of the iteration -> latency hidden)
      bf16x8 vc[4];
#pragma unroll
      for (int mtd = 0; mtd < 4; mtd++)
        vc[mtd] = *(const bf16x8*)(Vtb + (long)(mtd * 16 + l16) * vtstr + kbase + l4 * 8);

      // S^T tiles: A = K rows (m=key), B = Q rows (n=q)
      floatx4 sacc[2][4];
#pragma unroll
      for (int mt = 0; mt < 2; mt++)
#pragma unroll
        for (int qtt = 0; qtt < 4; qtt++) sacc[mt][qtt] = (floatx4){0.f, 0.f, 0.f, 0.f};
#pragma unroll
      for (int ds = 0; ds < 2; ds++)
#pragma unroll
        for (int mt = 0; mt < 2; mt++)
#pragma unroll
          for (int qtt = 0; qtt < 4; qtt++)
            sacc[mt][qtt] = __builtin_amdgcn_mfma_f32_16x16x32_bf16(kc[mt][ds], qf[qtt][ds], sacc[mt][qtt], 0, 0, 0);

      if (kt + 1 < nkt) {  // prefetch next K
        const int nb = kbase + 128;
#pragma unroll
        for (int mt = 0; mt < 2; mt++)
#pragma unroll
          for (int ds = 0; ds < 2; ds++)
            kn[mt][ds] = *(const bf16x8*)(Kb + (long)(nb + mt * 16 + l16) * kstr + ds * 32 + l4 * 8);
      }

      // causal mask (finite NEG; only last self tile straddles)
      if (phase == 0 && kt == nkt - 1) {
#pragma unroll
        for (int mt = 0; mt < 2; mt++) {
          int keyb = kbase + mt * 16 + l4 * 4;
#pragma unroll
          for (int qtt = 0; qtt < 4; qtt++) {
            int q = q0 + qtt * 16 + l16;
#pragma unroll
            for (int r = 0; r < 4; r++)
              if (keyb + r > q) sacc[mt][qtt][r] = NEG;
          }
        }
      }

      // per-wave online softmax (reduce across l4 lanes only: xor 16, 32)
      float alpha[4];
      unsigned pd[4][2][2];
      int changed = 0;
#pragma unroll
      for (int qtt = 0; qtt < 4; qtt++) {
        float mx = fmaxf(fmaxf(fmaxf(sacc[0][qtt][0], sacc[0][qtt][1]), fmaxf(sacc[0][qtt][2], sacc[0][qtt][3])),
                         fmaxf(fmaxf(sacc[1][qtt][0], sacc[1][qtt][1]), fmaxf(sacc[1][qtt][2], sacc[1][qtt][3])));
        mx = fmaxf(mx, __shfl_xor(mx, 16));
        mx = fmaxf(mx, __shfl_xor(mx, 32));
        mx = fmaxf(mx, m_i[qtt]);
        alpha[qtt] = EXP2(m_i[qtt] - mx);
        changed |= (mx > m_i[qtt]) ? 1 : 0;
        m_i[qtt] = mx;
        float rs = 0.f;
#pragma unroll
        for (int mt = 0; mt < 2; mt++) {
          float p0 = EXP2(sacc[mt][qtt][0] - mx), p1 = EXP2(sacc[mt][qtt][1] - mx);
          float p2 = EXP2(sacc[mt][qtt][2] - mx), p3 = EXP2(sacc[mt][qtt][3] - mx);
          rs += (p0 + p1) + (p2 + p3);
          pd[qtt][mt][0] = pack_bf16(p0, p1);
          pd[qtt][mt][1] = pack_bf16(p2, p3);
        }
        rs += __shfl_xor(rs, 16);
        rs += __shfl_xor(rs, 32);
        l_i[qtt] = l_i[qtt] * alpha[qtt] + rs;
      }
      if (__any(changed)) {
#pragma unroll
        for (int mtd = 0; mtd < 4; mtd++)
#pragma unroll
          for (int qtt = 0; qtt < 4; qtt++)
#pragma unroll
            for (int r = 0; r < 4; r++) oacc[mtd][qtt][r] *= alpha[qtt];
      }

      // P^T round-trip through wave-private slab (C layout -> B-frag layout)
#pragma unroll
      for (int qtt = 0; qtt < 4; qtt++)
#pragma unroll
        for (int mt = 0; mt < 2; mt++) {
          uint2 u = {pd[qtt][mt][0], pd[qtt][mt][1]};
          *(uint2*)&Pw[(qtt * 16 + l16) * 48 + mt * 16 + l4 * 4] = u;
        }
      // O^T += V^T · P^T over this wave's 32 keys (K=32 = one MFMA per tile)
#pragma unroll
      for (int qtt = 0; qtt < 4; qtt++) {
        bf16x8 pf = *(const bf16x8*)&Pw[(qtt * 16 + l16) * 48 + l4 * 8];
#pragma unroll
        for (int mtd = 0; mtd < 4; mtd++)
          oacc[mtd][qtt] = __builtin_amdgcn_mfma_f32_16x16x32_bf16(vc[mtd], pf, oacc[mtd][qtt], 0, 0, 0);
      }
#pragma unroll
      for (int mt = 0; mt < 2; mt++)
#pragma unroll
        for (int ds = 0; ds < 2; ds++) kc[mt][ds] = kn[mt][ds];
    }  // kt

    // ---- flash-combine across the 4 waves ----
    if (l4 == 0) {
#pragma unroll
      for (int qtt = 0; qtt < 4; qtt++) Mbuf[w][qtt][l16] = make_float2(m_i[qtt], l_i[qtt]);
    }
    __syncthreads();
    float myscale[4], denom[4];
#pragma unroll
    for (int qtt = 0; qtt < 4; qtt++) {
      float2 s0 = Mbuf[0][qtt][l16], s1 = Mbuf[1][qtt][l16];
      float2 s2 = Mbuf[2][qtt][l16], s3 = Mbuf[3][qtt][l16];
      float M = fmaxf(fmaxf(s0.x, s1.x), fmaxf(s2.x, s3.x));
      denom[qtt] = EXP2(s0.x - M) * s0.y + EXP2(s1.x - M) * s1.y +
                   EXP2(s2.x - M) * s2.y + EXP2(s3.x - M) * s3.y;
      myscale[qtt] = EXP2(m_i[qtt] - M);
    }
    // scaled O^T partials (bf16) -> Obuf[w][q][d]
#pragma unroll
    for (int qtt = 0; qtt < 4; qtt++)
#pragma unroll
      for (int mtd = 0; mtd < 4; mtd++) {
        float s = myscale[qtt];
        uint2 u = {pack_bf16(oacc[mtd][qtt][0] * s, oacc[mtd][qtt][1] * s),
                   pack_bf16(oacc[mtd][qtt][2] * s, oacc[mtd][qtt][3] * s)};
        *(uint2*)&U[((w * 64) + qtt * 16 + l16) * 72 + mtd * 16 + l4 * 4] = u;
      }
    __syncthreads();
    // owner: q = q0 + w*16 + l16, d = l4*16 .. +16
    float sum[16];
#pragma unroll
    for (int j = 0; j < 16; j++) sum[j] = 0.f;
#pragma unroll
    for (int s = 0; s < 4; s++) {
      bf16x8 c0 = *(const bf16x8*)&U[((s * 64) + w * 16 + l16) * 72 + l4 * 16];
      bf16x8 c1 = *(const bf16x8*)&U[((s * 64) + w * 16 + l16) * 72 + l4 * 16 + 8];
#pragma unroll
      for (int j = 0; j < 8; j++) { sum[j] += (float)c0[j]; sum[8 + j] += (float)c1[j]; }
    }
    float invd = 1.0f / denom[w];
    if (phase == 0) {
#pragma unroll
      for (int j = 0; j < 16; j++) o_self[j] = sum[j] * invd;
    } else {
      long row = (long)b * 2048 + q0 + w * 16 + l16;
      bf16 out[16];
#pragma unroll
      for (int j = 0; j < 16; j++) out[j] = (bf16)(o_self[j] + sum[j] * invd);
      *(bf16x8*)&Y[row * 1024 + h * 64 + l4 * 16] = *(const bf16x8*)&out[0];
      *(bf16x8*)&Y[row * 1024 + h * 64 + l4 * 16 + 8] = *(const bf16x8*)&out[8];
    }
  }  // phase
}

extern "C" void kernel_launch(void* const* d_in, const int* in_sizes, int n_in,
                              void* d_out, int out_size, void* d_ws, size_t ws_size,
                              hipStream_t stream) {
  const float* x   = (const float*)d_in[0];
  const float* xc  = (const float*)d_in[1];
  const float* Wk  = (const float*)d_in[2];  const float* bk  = (const float*)d_in[3];
  const float* Wq  = (const float*)d_in[4];  const float* bq  = (const float*)d_in[5];
  const float* Wv  = (const float*)d_in[6];  const float* bv  = (const float*)d_in[7];
  const float* Wck = (const float*)d_in[8];  const float* bck = (const float*)d_in[9];
  const float* Wcq = (const float*)d_in[10]; const float* bcq = (const float*)d_in[11];
  const float* Wcv = (const float*)d_in[12]; const float* bcv = (const float*)d_in[13];
  const float* Wp  = (const float*)d_in[14]; const float* bp  = (const float*)d_in[15];

  char* ws = (char*)d_ws;
  const size_t MB = 1ull << 20;
  bf16*  WT_all = (bf16*)(ws + 0);         // [4096][1024]: Q|K|V|Qc
  bf16*  WC_all = (bf16*)(ws + 8 * MB);    // [2048][512]: Kc|Vc
  bf16*  WpT    = (bf16*)(ws + 10 * MB);   // [1024][1024]
  bf16*  xbf    = (bf16*)(ws + 12 * MB);   // [4096][1024]; Yb overlays after projections
  bf16*  Yb     = xbf;
  bf16*  xcbf   = (bf16*)(ws + 20 * MB);   // [1024][512]
  float* bias4  = (float*)(ws + 21 * MB);          // [4096]: bq|bk|bv|bcq
  float* biasc  = (float*)(ws + 21 * MB + 65536);  // [2048]: bck|bcv
  bf16*  QKQc   = (bf16*)(ws + 22 * MB);   // [4096][3072]: Q|K|Qc (compacted)
  bf16*  VtB    = (bf16*)(ws + 46 * MB);   // [2][16][64][2048]
  bf16*  KcB    = (bf16*)(ws + 54 * MB);   // [1024][1024]
  bf16*  VctB   = (bf16*)(ws + 56 * MB);   // [2][16][64][512]

  PrepArgs pa;
  pa.x = x; pa.xc = xc; pa.xbf = xbf; pa.xcbf = xcbf;
  pa.b4[0] = bq; pa.b4[1] = bk; pa.b4[2] = bv; pa.b4[3] = bcq;
  pa.bc[0] = bck; pa.bc[1] = bcv;
  pa.bias4 = bias4; pa.biasc = biasc;
  pa.W[0] = Wq;  pa.WT[0] = WT_all + 0ll * 1024 * 1024;
  pa.W[1] = Wk;  pa.WT[1] = WT_all + 1ll * 1024 * 1024;
  pa.W[2] = Wv;  pa.WT[2] = WT_all + 2ll * 1024 * 1024;
  pa.W[3] = Wcq; pa.WT[3] = WT_all + 3ll * 1024 * 1024;
  pa.W[4] = Wp;  pa.WT[4] = WpT;
  pa.W[5] = Wck; pa.WT[5] = WC_all + 0ll * 1024 * 512;
  pa.W[6] = Wcv; pa.WT[6] = WC_all + 1ll * 1024 * 512;
  prep_kernel<<<10776, 256, 0, stream>>>(pa);

  // fused QKV+Qc projection: N=4096; V section [2048,3072) -> VtB transposed
  gemm128<bf16><<<dim3(32, 32), 256, 0, stream>>>(xbf, WT_all, bias4, QKQc,
                                                  4096, 4096, 1024, 3072,
                                                  VtB, 2048, 3072, 2048, 11);
  // fused cross K+V: N=2048; Vc section [1024,2048) -> VctB transposed
  gemm128<bf16><<<dim3(16, 8), 256, 0, stream>>>(xcbf, WC_all, biasc, KcB,
                                                 1024, 2048, 512, 1024,
                                                 VctB, 1024, 2048, 512, 9);

  attn_kernel<<<dim3(32, 32), 256, 0, stream>>>(QKQc, VtB, KcB, VctB, Yb);

  gemm128<float><<<dim3(8, 32), 256, 0, stream>>>(Yb, WpT, bp, (float*)d_out,
                                                  4096, 1024, 1024, 1024,
                                                  nullptr, -1, -1, 0, 0);
}